// Round 2
// baseline (6699.036 us; speedup 1.0000x reference)
//
#include <hip/hip_runtime.h>

// SchNet on MI355X — round 2: fp32 skeleton + runtime input-dtype detection
// (fp32 vs bf16 buffers, int32 vs int64 edge_index). CSR-gather aggregation,
// SGPR-weight FMA kernels. Round-3 target: bf16 MFMA for k_wf (dominant).

#define NN 10000
#define EE 320000
#define HH 128
#define GG 50
#define NF 128
#define NL 6
#define TLSS 130   // LDS column stride (u16): 2 lanes/bank -> free

typedef unsigned short u16;
typedef unsigned int u32;

__device__ __forceinline__ float us2f(u16 u){
  union { float f; u32 i; } v; v.i = ((u32)u) << 16; return v.f;
}
__device__ __forceinline__ u16 f2us(float x){
  union { float f; u32 i; } v; v.f = x;
  u32 r = v.i + 0x7fffu + ((v.i >> 16) & 1u);   // RNE
  return (u16)(r >> 16);
}
// value i of a logical float array that may be stored fp32 or bf16
__device__ __forceinline__ float ldin(const void* p, int i, int bf){
  return bf ? us2f(((const u16*)p)[i]) : ((const float*)p)[i];
}
// ShiftedSoftplus: softplus(x) - ln2, numerically stable
__device__ __forceinline__ float sspf(float x){
  return fmaxf(x, 0.f) + log1pf(__expf(-fabsf(x))) - 0.693147180559945f;
}

// ---------- dtype detection: flags[0]=inputs-are-bf16, flags[1]=edge-is-int64 ----------
// bf16 test: low u16 of each word has bits[14:8] (exp[7:1]) near 0x3E for N(0,1)
// data (~99% in [0x38,0x41]); fp32 mantissa noise hits that range ~8%.
__global__ void k_dtype(const u32* __restrict__ zraw, const int* __restrict__ ei_raw,
                        int* __restrict__ flags){
  __shared__ int votes[2];
  if(threadIdx.x < 2) votes[threadIdx.x] = 0;
  __syncthreads();
  int v0 = 0, v1 = 0;
  for(int i = threadIdx.x; i < 4096; i += 256){
    u32 w = zraw[i];
    u32 hb = (w >> 8) & 0x7F;
    if(hb >= 0x38 && hb <= 0x41) v0++;
    if(ei_raw[2*i + 1] == 0) v1++;       // int64 LE: odd int32 slots all zero
  }
  atomicAdd(&votes[0], v0); atomicAdd(&votes[1], v1);
  __syncthreads();
  if(threadIdx.x == 0){
    flags[0] = (votes[0] > 2048) ? 1 : 0;
    flags[1] = (votes[1] > 4000) ? 1 : 0;
  }
}

__global__ void k_norm(const int* __restrict__ ei_raw, const int* __restrict__ flags,
                       int* __restrict__ eiN){
  int j = blockIdx.x*256 + threadIdx.x;           // grid exact: 2*EE
  int is64 = flags[1];
  eiN[j] = is64 ? ei_raw[2*j] : ei_raw[j];
}

// ---------- weight staging: ->fp32, transpose to [k][f] where needed ----------
__global__ void k_prep_weights(
    const void* __restrict__ mlp1_w, const void* __restrict__ mlp1_b,
    const void* __restrict__ mlp2_w, const void* __restrict__ mlp2_b,
    const void* __restrict__ lin1_w, const void* __restrict__ lin2_w,
    const void* __restrict__ lin2_b, const void* __restrict__ lin_w,
    const void* __restrict__ lin_b,  const void* __restrict__ coord_w,
    const void* __restrict__ coord_b, const int* __restrict__ flags,
    float* __restrict__ w1f, float* __restrict__ b1f,
    float* __restrict__ w2t, float* __restrict__ b2v,
    float* __restrict__ l1t, float* __restrict__ l2t,
    float* __restrict__ l2bf, float* __restrict__ lwt,
    float* __restrict__ lbf, float* __restrict__ cwf, float* __restrict__ cbf)
{
  int i = blockIdx.x*256 + threadIdx.x;           // grid exact: NL*NF*NF
  int bf = flags[0];
  if(i < NL*NF*GG) w1f[i] = ldin(mlp1_w, i, bf);  // keep [l][f][g]
  if(i < NL*NF){
    b1f[i]  = ldin(mlp1_b, i, bf);
    b2v[i]  = ldin(mlp2_b, i, bf);
    l2bf[i] = ldin(lin2_b, i, bf);
    lbf[i]  = ldin(lin_b,  i, bf);
  }
  if(i < NL*NF*NF){
    int l = i/(NF*NF), rem = i%(NF*NF);
    int k = rem/NF, f = rem%NF;                   // X_t[l][k][f] = X[l][f][k]
    w2t[i] = ldin(mlp2_w, l*NF*NF + f*NF + k, bf);
    l1t[i] = ldin(lin1_w, l*NF*HH + f*HH + k, bf);
    l2t[i] = ldin(lin2_w, l*HH*NF + f*NF + k, bf);
    lwt[i] = ldin(lin_w,  l*HH*HH + f*HH + k, bf);
  }
  if(i < NL*(GG+2*HH)) cwf[i] = ldin(coord_w, i, bf);
  if(i < NL) cbf[i] = ldin(coord_b, i, bf);
}

__global__ void k_init(const void* __restrict__ z, const void* __restrict__ pos_in,
                       const int* __restrict__ flags,
                       float* __restrict__ h, float* __restrict__ pos){
  int i = blockIdx.x*256 + threadIdx.x;           // grid exact: NN*HH
  int bf = flags[0];
  h[i] = ldin(z, i, bf);
  if(i < NN*3) pos[i] = ldin(pos_in, i, bf);
}

// ---------- edge prep: distances (INITIAL pos), cosine cutoff, degrees ----------
__global__ void k_edge_prep(const int* __restrict__ eiN, const float* __restrict__ pos,
                            float* __restrict__ wE, float* __restrict__ cE,
                            int* __restrict__ deg_row, int* __restrict__ col_deg){
  int e = blockIdx.x*256 + threadIdx.x;           // grid exact: EE
  int r = eiN[e], c = eiN[EE+e];
  float dx = pos[r*3+0]-pos[c*3+0];
  float dy = pos[r*3+1]-pos[c*3+1];
  float dz = pos[r*3+2]-pos[c*3+2];
  float w = sqrtf(dx*dx + dy*dy + dz*dz);
  wE[e] = w;
  cE[e] = 0.5f*(cosf(w*0.3141592653589793f) + 1.f);
  atomicAdd(&deg_row[r], 1);
  atomicAdd(&col_deg[c], 1);
}

// ---------- single-block exclusive scan over col_deg (N=10000) ----------
__global__ void k_scan(const int* __restrict__ col_deg, int* __restrict__ col_start,
                       int* __restrict__ col_next){
  __shared__ int part[1024];
  int tid = threadIdx.x;
  const int CH = (NN + 1023)/1024;                // 10
  int base = tid*CH;
  int s = 0;
  for(int i=0;i<CH;i++){ int idx=base+i; if(idx<NN) s += col_deg[idx]; }
  part[tid] = s;
  __syncthreads();
  for(int off=1; off<1024; off<<=1){
    int v = (tid>=off) ? part[tid-off] : 0;
    __syncthreads();
    part[tid] += v;
    __syncthreads();
  }
  int run = (tid==0) ? 0 : part[tid-1];
  for(int i=0;i<CH;i++){
    int idx = base+i;
    if(idx<NN){ col_start[idx]=run; col_next[idx]=run; run += col_deg[idx]; }
  }
  if(tid==1023) col_start[NN] = run;
}

__global__ void k_fill(const int* __restrict__ eiN, int* __restrict__ col_next,
                       int* __restrict__ eids){
  int e = blockIdx.x*256 + threadIdx.x;           // grid exact: EE
  int c = eiN[EE+e];
  int p = atomicAdd(&col_next[c], 1);
  eids[p] = e;
}

// permute edge data into CSR (col-sorted) order
__global__ void k_sort(const int* __restrict__ eids, const int* __restrict__ eiN,
                       const float* __restrict__ wE, const float* __restrict__ cE,
                       int* __restrict__ row_s, float* __restrict__ wEs,
                       float* __restrict__ cEs){
  int p = blockIdx.x*256 + threadIdx.x;           // grid exact: EE
  int e = eids[p];
  row_s[p] = eiN[e];
  wEs[p] = wE[e];
  cEs[p] = cE[e];
}

// ---------- per-layer: coordinate update (wave per edge) ----------
__global__ void k_coord(const int* __restrict__ eiN, const float* __restrict__ h,
                        const float* __restrict__ pos, const float* __restrict__ wE,
                        const float* __restrict__ cwf, const float* __restrict__ cbf,
                        int l, float* __restrict__ sums){
  int lane = threadIdx.x & 63;
  int e = (blockIdx.x*256 + threadIdx.x) >> 6;    // grid exact: EE waves
  const float* __restrict__ cw = cwf + l*(GG + 2*HH);
  int r = eiN[e];
  int c = eiN[EE + e];
  float w = wE[e];
  float acc = 0.f;
  if(lane < GG){
    float d = w - (float)lane*(10.f/49.f);
    acc = __expf(-12.005f*d*d) * cw[lane];
  }
  acc += h[r*HH + lane]      * cw[GG + lane];
  acc += h[r*HH + 64 + lane] * cw[GG + 64 + lane];
  acc += h[c*HH + lane]      * cw[GG + HH + lane];
  acc += h[c*HH + 64 + lane] * cw[GG + HH + 64 + lane];
  #pragma unroll
  for(int s=32; s>0; s>>=1) acc += __shfl_down(acc, s, 64);
  if(lane == 0){
    float cv = acc + cbf[l];
    atomicAdd(&sums[r*3+0], (pos[r*3+0]-pos[c*3+0])*cv);
    atomicAdd(&sums[r*3+1], (pos[r*3+1]-pos[c*3+1])*cv);
    atomicAdd(&sums[r*3+2], (pos[r*3+2]-pos[c*3+2])*cv);
  }
}

__global__ void k_posupd(float* __restrict__ pos, const float* __restrict__ sums,
                         const int* __restrict__ deg_row){
  int n = blockIdx.x*256 + threadIdx.x;
  if(n >= NN) return;
  int d = deg_row[n];
  if(d > 0){
    float inv = 1.f/(float)d;
    pos[n*3+0] += sums[n*3+0]*inv;
    pos[n*3+1] += sums[n*3+1]*inv;
    pos[n*3+2] += sums[n*3+2]*inv;
  }
}

// ---------- xf = h @ lin1^T : 8 nodes/block, h via SGPR, weights coalesced ----------
__global__ void k_xf(const float* __restrict__ h, const float* __restrict__ l1t,
                     int l, float* __restrict__ xf){
  int f = threadIdx.x;
  int n0 = blockIdx.x*8;                          // grid exact: NN/8
  const float* __restrict__ wt = l1t + l*HH*NF;
  float acc[8];
  #pragma unroll
  for(int i=0;i<8;i++) acc[i] = 0.f;
  for(int k=0;k<HH;k++){
    float wv = wt[k*NF + f];
    #pragma unroll
    for(int i=0;i<8;i++) acc[i] += h[(n0+i)*HH + k] * wv;   // h: uniform -> s_load
  }
  #pragma unroll
  for(int i=0;i<8;i++) xf[(n0+i)*NF + f] = acc[i];
}

// ---------- edge MLP: thread per edge (CSR order), weights via SGPR ----------
__global__ void k_wf(const float* __restrict__ wEs, const float* __restrict__ cEs,
                     const float* __restrict__ w1f, const float* __restrict__ b1f,
                     const float* __restrict__ w2t, const float* __restrict__ b2v,
                     int l, u16* __restrict__ WfT){
  __shared__ u16 tls[NF*TLSS];
  int tid = threadIdx.x;
  int p = blockIdx.x*128 + tid;                   // grid exact: EE/128
  float w = wEs[p];
  float attr[GG];
  #pragma unroll
  for(int g=0; g<GG; g++){
    float d = w - (float)g*(10.f/49.f);
    attr[g] = __expf(-12.005f*d*d);               // coeff = -0.5/(10/49)^2
  }
  const float* __restrict__ w1 = w1f + l*NF*GG;
  const float* __restrict__ b1 = b1f + l*NF;
  for(int f=0; f<NF; f++){
    float a0 = b1[f], a1 = 0.f;
    #pragma unroll
    for(int g=0; g<GG; g+=2){
      a0 += attr[g]   * w1[f*GG + g];
      a1 += attr[g+1] * w1[f*GG + g + 1];
    }
    tls[f*TLSS + tid] = f2us(sspf(a0 + a1));
  }
  const float* __restrict__ w2 = w2t + l*NF*NF;
  const float* __restrict__ b2 = b2v + l*NF;
  float cc = cEs[p];
  for(int f0=0; f0<NF; f0+=32){
    float acc[32];
    #pragma unroll
    for(int j=0;j<32;j++) acc[j] = b2[f0+j];
    for(int k=0;k<NF;k++){
      float tv = us2f(tls[k*TLSS + tid]);
      #pragma unroll
      for(int j=0;j<32;j++) acc[j] += tv * w2[k*NF + f0 + j];  // w2: s_load runs
    }
    #pragma unroll
    for(int j=0;j<32;j++) WfT[(f0+j)*EE + p] = f2us(acc[j]*cc);
  }
}

// ---------- agg[n] = sum over incoming edges of xf[row]*Wf (atomic-free) ----------
__global__ void k_gather(const int* __restrict__ col_start, const int* __restrict__ row_s,
                         const float* __restrict__ xf, const u16* __restrict__ WfT,
                         float* __restrict__ agg){
  int n = blockIdx.x;                             // grid: NN
  int f = threadIdx.x;
  int p0 = col_start[n], p1 = col_start[n+1];
  float acc = 0.f;
  for(int p=p0; p<p1; p++){
    int r = row_s[p];                             // uniform -> s_load
    acc += xf[r*NF + f] * us2f(WfT[f*EE + p]);    // per-lane contiguous bf16 stream
  }
  agg[n*NF + f] = acc;
}

// ---------- h += ssp(agg@lin2^T + b) @ lin^T + b : 8 nodes/block ----------
__global__ void k_update(const float* __restrict__ agg, const float* __restrict__ l2t,
                         const float* __restrict__ l2bf, const float* __restrict__ lwt,
                         const float* __restrict__ lbf, int l, float* __restrict__ h){
  __shared__ float sg[HH*12];
  int f = threadIdx.x;
  int n0 = blockIdx.x*8;                          // grid exact: NN/8
  const float* __restrict__ wA = l2t + l*NF*HH;
  float bA = l2bf[l*HH + f];
  float acc[8];
  #pragma unroll
  for(int i=0;i<8;i++) acc[i] = bA;
  for(int k=0;k<NF;k++){
    float wv = wA[k*HH + f];
    #pragma unroll
    for(int i=0;i<8;i++) acc[i] += agg[(n0+i)*NF + k] * wv;  // agg uniform -> s_load
  }
  #pragma unroll
  for(int i=0;i<8;i++) sg[f*12 + i] = sspf(acc[i]);
  __syncthreads();
  const float* __restrict__ wB = lwt + l*HH*HH;
  float bB = lbf[l*HH + f];
  float acc2[8];
  #pragma unroll
  for(int i=0;i<8;i++) acc2[i] = bB;
  for(int k=0;k<HH;k++){
    float wv = wB[k*HH + f];
    #pragma unroll
    for(int i=0;i<8;i++) acc2[i] += sg[k*12 + i] * wv;       // broadcast LDS reads
  }
  #pragma unroll
  for(int i=0;i<8;i++) h[(n0+i)*HH + f] += acc2[i];
}

__global__ void k_out(const float* __restrict__ pos, const float* __restrict__ h,
                      const int* __restrict__ flags, void* __restrict__ out){
  int i = blockIdx.x*256 + threadIdx.x;           // grid exact: NN*HH
  int bf = flags[0];
  if(bf){
    u16* o = (u16*)out;
    if(i < NN*3) o[i] = f2us(pos[i]);
    o[NN*3 + i] = f2us(h[i]);
  } else {
    float* o = (float*)out;
    if(i < NN*3) o[i] = pos[i];
    o[NN*3 + i] = h[i];
  }
}

extern "C" void kernel_launch(void* const* d_in, const int* in_sizes, int n_in,
                              void* d_out, int out_size, void* d_ws, size_t ws_size,
                              hipStream_t stream){
  const void* z      = d_in[0];
  const void* pos_in = d_in[1];
  const int*  ei_raw = (const int*)d_in[2];
  const void* mlp1_w = d_in[3];
  const void* mlp1_b = d_in[4];
  const void* mlp2_w = d_in[5];
  const void* mlp2_b = d_in[6];
  const void* lin1_w = d_in[7];
  const void* lin2_w = d_in[8];
  const void* lin2_b = d_in[9];
  const void* lin_w  = d_in[10];
  const void* lin_b  = d_in[11];
  const void* coord_w= d_in[12];
  const void* coord_b= d_in[13];

  float* W = (float*)d_ws;
  float* h    = W; W += NN*HH;
  float* xf   = W; W += NN*NF;
  float* agg  = W; W += NN*NF;
  float* pos  = W; W += NN*3;
  float* sums = W; W += NN*3;
  float* wE   = W; W += EE;
  float* cE   = W; W += EE;
  float* wEs  = W; W += EE;
  float* cEs  = W; W += EE;
  float* w1f  = W; W += NL*NF*GG;
  float* b1f  = W; W += NL*NF;
  float* w2t  = W; W += NL*NF*NF;
  float* b2v  = W; W += NL*NF;
  float* l1t  = W; W += NL*NF*HH;
  float* l2t  = W; W += NL*HH*NF;
  float* l2bf = W; W += NL*HH;
  float* lwt  = W; W += NL*HH*HH;
  float* lbf  = W; W += NL*HH;
  float* cwf  = W; W += NL*(GG+2*HH);
  float* cbf  = W; W += NL;
  u16*  WfT   = (u16*)W; W += (EE*NF)/2;          // E*NF bf16
  int* deg_row   = (int*)W; W += NN;
  int* col_deg   = (int*)W; W += NN;
  int* col_start = (int*)W; W += NN+1;
  int* col_next  = (int*)W; W += NN;
  int* eids      = (int*)W; W += EE;
  int* row_s     = (int*)W; W += EE;
  int* eiN       = (int*)W; W += 2*EE;
  int* flags     = (int*)W; W += 2;

  hipMemsetAsync(deg_row, 0, NN*sizeof(int), stream);
  hipMemsetAsync(col_deg, 0, NN*sizeof(int), stream);

  k_dtype<<<1, 256, 0, stream>>>((const u32*)z, ei_raw, flags);
  k_norm<<<(2*EE)/256, 256, 0, stream>>>(ei_raw, flags, eiN);
  k_prep_weights<<<(NL*NF*NF)/256, 256, 0, stream>>>(
      mlp1_w, mlp1_b, mlp2_w, mlp2_b, lin1_w, lin2_w, lin2_b, lin_w, lin_b,
      coord_w, coord_b, flags,
      w1f, b1f, w2t, b2v, l1t, l2t, l2bf, lwt, lbf, cwf, cbf);
  k_init<<<(NN*HH)/256, 256, 0, stream>>>(z, pos_in, flags, h, pos);
  k_edge_prep<<<EE/256, 256, 0, stream>>>(eiN, pos, wE, cE, deg_row, col_deg);
  k_scan<<<1, 1024, 0, stream>>>(col_deg, col_start, col_next);
  k_fill<<<EE/256, 256, 0, stream>>>(eiN, col_next, eids);
  k_sort<<<EE/256, 256, 0, stream>>>(eids, eiN, wE, cE, row_s, wEs, cEs);

  for(int l=0; l<NL; l++){
    hipMemsetAsync(sums, 0, NN*3*sizeof(float), stream);
    k_coord<<<EE/4, 256, 0, stream>>>(eiN, h, pos, wE, cwf, cbf, l, sums);
    k_posupd<<<(NN+255)/256, 256, 0, stream>>>(pos, sums, deg_row);
    k_xf<<<NN/8, 128, 0, stream>>>(h, l1t, l, xf);
    k_wf<<<EE/128, 128, 0, stream>>>(wEs, cEs, w1f, b1f, w2t, b2v, l, WfT);
    k_gather<<<NN, 128, 0, stream>>>(col_start, row_s, xf, WfT, agg);
    k_update<<<NN/8, 128, 0, stream>>>(agg, l2t, l2bf, lwt, lbf, l, h);
  }
  k_out<<<(NN*HH)/256, 256, 0, stream>>>(pos, h, flags, (void*)d_out);
}

// Round 3
// 1869.026 us; speedup vs baseline: 3.5842x; 3.5842x over previous
//
#include <hip/hip_runtime.h>

// SchNet on MI355X — round 3: bf16-MFMA edge MLP (k_wf) + coalesced edge-major
// gather. Runtime input-dtype detection retained (fp32 vs bf16, int32 vs int64).

#define NN 10000
#define EE 320000
#define HH 128
#define GG 50
#define NF 128
#define NL 6

typedef unsigned short u16;
typedef unsigned int u32;
typedef short bf16x8 __attribute__((ext_vector_type(8)));
typedef float f32x4  __attribute__((ext_vector_type(4)));

__device__ __forceinline__ float us2f(u16 u){
  union { float f; u32 i; } v; v.i = ((u32)u) << 16; return v.f;
}
__device__ __forceinline__ u16 f2us(float x){
  union { float f; u32 i; } v; v.f = x;
  u32 r = v.i + 0x7fffu + ((v.i >> 16) & 1u);   // RNE
  return (u16)(r >> 16);
}
__device__ __forceinline__ float ldin(const void* p, int i, int bf){
  return bf ? us2f(((const u16*)p)[i]) : ((const float*)p)[i];
}
// ShiftedSoftplus: softplus(x) - ln2 via fast hw exp/log
__device__ __forceinline__ float sspf(float x){
  return fmaxf(x, 0.f) + __logf(1.f + __expf(-fabsf(x))) - 0.6931472f;
}

// ---------- dtype detection: flags[0]=inputs-bf16, flags[1]=edge-int64 ----------
__global__ void k_dtype(const u32* __restrict__ zraw, const int* __restrict__ ei_raw,
                        int* __restrict__ flags){
  __shared__ int votes[2];
  if(threadIdx.x < 2) votes[threadIdx.x] = 0;
  __syncthreads();
  int v0 = 0, v1 = 0;
  for(int i = threadIdx.x; i < 4096; i += 256){
    u32 w = zraw[i];
    u32 hb = (w >> 8) & 0x7F;
    if(hb >= 0x38 && hb <= 0x41) v0++;
    if(ei_raw[2*i + 1] == 0) v1++;
  }
  atomicAdd(&votes[0], v0); atomicAdd(&votes[1], v1);
  __syncthreads();
  if(threadIdx.x == 0){
    flags[0] = (votes[0] > 2048) ? 1 : 0;
    flags[1] = (votes[1] > 4000) ? 1 : 0;
  }
}

__global__ void k_norm(const int* __restrict__ ei_raw, const int* __restrict__ flags,
                       int* __restrict__ eiN){
  int j = blockIdx.x*256 + threadIdx.x;           // grid exact: 2*EE
  eiN[j] = flags[1] ? ei_raw[2*j] : ei_raw[j];
}

// ---------- weight staging ----------
__global__ void k_prep_weights(
    const void* __restrict__ mlp1_w, const void* __restrict__ mlp1_b,
    const void* __restrict__ mlp2_w, const void* __restrict__ mlp2_b,
    const void* __restrict__ lin1_w, const void* __restrict__ lin2_w,
    const void* __restrict__ lin2_b, const void* __restrict__ lin_w,
    const void* __restrict__ lin_b,  const void* __restrict__ coord_w,
    const void* __restrict__ coord_b, const int* __restrict__ flags,
    float* __restrict__ b1f, float* __restrict__ b2v,
    float* __restrict__ l1t, float* __restrict__ l2t,
    float* __restrict__ l2bf, float* __restrict__ lwt,
    float* __restrict__ lbf, float* __restrict__ cwf, float* __restrict__ cbf,
    u16* __restrict__ w1b, u16* __restrict__ w2b)
{
  int i = blockIdx.x*256 + threadIdx.x;           // grid exact: NL*NF*NF
  int bf = flags[0];
  if(i < NL*NF){
    b1f[i]  = ldin(mlp1_b, i, bf);
    b2v[i]  = ldin(mlp2_b, i, bf);
    l2bf[i] = ldin(lin2_b, i, bf);
    lbf[i]  = ldin(lin_b,  i, bf);
  }
  if(i < NL*NF*64){                               // W1 bf16, K padded 50->64
    int l = i/(NF*64), rem = i%(NF*64);
    int f = rem/64, k = rem%64;
    w1b[i] = (k < GG) ? f2us(ldin(mlp1_w, (l*NF + f)*GG + k, bf)) : (u16)0;
  }
  if(i < NL*NF*NF){
    w2b[i] = f2us(ldin(mlp2_w, i, bf));           // [l][n][k] row-major
    int l = i/(NF*NF), rem = i%(NF*NF);
    int k = rem/NF, f = rem%NF;                   // X_t[l][k][f] = X[l][f][k]
    l1t[i] = ldin(lin1_w, l*NF*HH + f*HH + k, bf);
    l2t[i] = ldin(lin2_w, l*HH*NF + f*NF + k, bf);
    lwt[i] = ldin(lin_w,  l*HH*HH + f*HH + k, bf);
  }
  if(i < NL*(GG+2*HH)) cwf[i] = ldin(coord_w, i, bf);
  if(i < NL) cbf[i] = ldin(coord_b, i, bf);
}

__global__ void k_init(const void* __restrict__ z, const void* __restrict__ pos_in,
                       const int* __restrict__ flags,
                       float* __restrict__ h, float* __restrict__ pos){
  int i = blockIdx.x*256 + threadIdx.x;           // grid exact: NN*HH
  int bf = flags[0];
  h[i] = ldin(z, i, bf);
  if(i < NN*3) pos[i] = ldin(pos_in, i, bf);
}

// ---------- edge prep ----------
__global__ void k_edge_prep(const int* __restrict__ eiN, const float* __restrict__ pos,
                            float* __restrict__ wE, float* __restrict__ cE,
                            int* __restrict__ deg_row, int* __restrict__ col_deg){
  int e = blockIdx.x*256 + threadIdx.x;           // grid exact: EE
  int r = eiN[e], c = eiN[EE+e];
  float dx = pos[r*3+0]-pos[c*3+0];
  float dy = pos[r*3+1]-pos[c*3+1];
  float dz = pos[r*3+2]-pos[c*3+2];
  float w = sqrtf(dx*dx + dy*dy + dz*dz);
  wE[e] = w;
  cE[e] = 0.5f*(cosf(w*0.3141592653589793f) + 1.f);
  atomicAdd(&deg_row[r], 1);
  atomicAdd(&col_deg[c], 1);
}

__global__ void k_scan(const int* __restrict__ col_deg, int* __restrict__ col_start,
                       int* __restrict__ col_next){
  __shared__ int part[1024];
  int tid = threadIdx.x;
  const int CH = (NN + 1023)/1024;
  int base = tid*CH;
  int s = 0;
  for(int i=0;i<CH;i++){ int idx=base+i; if(idx<NN) s += col_deg[idx]; }
  part[tid] = s;
  __syncthreads();
  for(int off=1; off<1024; off<<=1){
    int v = (tid>=off) ? part[tid-off] : 0;
    __syncthreads();
    part[tid] += v;
    __syncthreads();
  }
  int run = (tid==0) ? 0 : part[tid-1];
  for(int i=0;i<CH;i++){
    int idx = base+i;
    if(idx<NN){ col_start[idx]=run; col_next[idx]=run; run += col_deg[idx]; }
  }
  if(tid==1023) col_start[NN] = run;
}

__global__ void k_fill(const int* __restrict__ eiN, int* __restrict__ col_next,
                       int* __restrict__ eids){
  int e = blockIdx.x*256 + threadIdx.x;           // grid exact: EE
  int c = eiN[EE+e];
  int p = atomicAdd(&col_next[c], 1);
  eids[p] = e;
}

__global__ void k_sort(const int* __restrict__ eids, const int* __restrict__ eiN,
                       const float* __restrict__ wE, const float* __restrict__ cE,
                       int* __restrict__ row_s, float* __restrict__ wEs,
                       float* __restrict__ cEs){
  int p = blockIdx.x*256 + threadIdx.x;           // grid exact: EE
  int e = eids[p];
  row_s[p] = eiN[e];
  wEs[p] = wE[e];
  cEs[p] = cE[e];
}

// ---------- coordinate update (wave per edge) ----------
__global__ void k_coord(const int* __restrict__ eiN, const float* __restrict__ h,
                        const float* __restrict__ pos, const float* __restrict__ wE,
                        const float* __restrict__ cwf, const float* __restrict__ cbf,
                        int l, float* __restrict__ sums){
  int lane = threadIdx.x & 63;
  int e = (blockIdx.x*256 + threadIdx.x) >> 6;    // grid exact: EE waves
  const float* __restrict__ cw = cwf + l*(GG + 2*HH);
  int r = eiN[e];
  int c = eiN[EE + e];
  float w = wE[e];
  float acc = 0.f;
  if(lane < GG){
    float d = w - (float)lane*(10.f/49.f);
    acc = __expf(-12.005f*d*d) * cw[lane];
  }
  acc += h[r*HH + lane]      * cw[GG + lane];
  acc += h[r*HH + 64 + lane] * cw[GG + 64 + lane];
  acc += h[c*HH + lane]      * cw[GG + HH + lane];
  acc += h[c*HH + 64 + lane] * cw[GG + HH + 64 + lane];
  #pragma unroll
  for(int s=32; s>0; s>>=1) acc += __shfl_down(acc, s, 64);
  if(lane == 0){
    float cv = acc + cbf[l];
    atomicAdd(&sums[r*3+0], (pos[r*3+0]-pos[c*3+0])*cv);
    atomicAdd(&sums[r*3+1], (pos[r*3+1]-pos[c*3+1])*cv);
    atomicAdd(&sums[r*3+2], (pos[r*3+2]-pos[c*3+2])*cv);
  }
}

__global__ void k_posupd(float* __restrict__ pos, const float* __restrict__ sums,
                         const int* __restrict__ deg_row){
  int n = blockIdx.x*256 + threadIdx.x;
  if(n >= NN) return;
  int d = deg_row[n];
  if(d > 0){
    float inv = 1.f/(float)d;
    pos[n*3+0] += sums[n*3+0]*inv;
    pos[n*3+1] += sums[n*3+1]*inv;
    pos[n*3+2] += sums[n*3+2]*inv;
  }
}

// ---------- xf = h @ lin1^T ----------
__global__ void k_xf(const float* __restrict__ h, const float* __restrict__ l1t,
                     int l, float* __restrict__ xf){
  int f = threadIdx.x;
  int n0 = blockIdx.x*8;                          // grid exact: NN/8
  const float* __restrict__ wt = l1t + l*HH*NF;
  float acc[8];
  #pragma unroll
  for(int i=0;i<8;i++) acc[i] = 0.f;
  for(int k=0;k<HH;k++){
    float wv = wt[k*NF + f];
    #pragma unroll
    for(int i=0;i<8;i++) acc[i] += h[(n0+i)*HH + k] * wv;
  }
  #pragma unroll
  for(int i=0;i<8;i++) xf[(n0+i)*NF + f] = acc[i];
}

// ---------- edge MLP via bf16 MFMA: 64 edges/block, 4 waves, 16 rows/wave ----------
// GEMM1: T = ssp(attr @ W1^T + b1)  [M=64,K=64(pad),N=128]
// GEMM2: Wf = (T @ W2^T + b2)*C     [M=64,K=128,N=128], edge-major output
// Frag layouts (m89/m91-verified): A[m=lane&15][k=quad*8+j], B[n=lane&15][k=quad*8+j],
// D: col=lane&15, row=quad*4+reg. Each wave stages & consumes its own 16 rows -> no barrier.
__global__ void k_wf(const float* __restrict__ wEs, const float* __restrict__ cEs,
                     const u16* __restrict__ w1b, const float* __restrict__ b1f,
                     const u16* __restrict__ w2b, const float* __restrict__ b2v,
                     int l, u16* __restrict__ Wf){
  __shared__ __align__(16) u16 A1[64*72];         // attrs, stride 72 (2-way bank = free)
  __shared__ __align__(16) u16 A2[64*136];        // T,     stride 136
  int p0 = blockIdx.x*64;                         // grid exact: EE/64
  int t = threadIdx.x;

  // phase 0: attrs -> A1 (each wave writes exactly its own 16 rows)
  {
    int e_loc = t >> 2;
    int c0 = (t & 3) * 16;
    float w = wEs[p0 + e_loc];
    #pragma unroll
    for(int j=0;j<16;j++){
      int g = c0 + j;
      float v = 0.f;
      if(g < GG){ float d = w - (float)g*(10.f/49.f); v = __expf(-12.005f*d*d); }
      A1[e_loc*72 + g] = f2us(v);
    }
  }

  int lane = t & 63;
  int m16  = lane & 15;
  int quad = lane >> 4;
  int m0   = (t >> 6) * 16;                       // wave's row base

  // phase 1: GEMM1 + ssp -> A2
  {
    const float* __restrict__ b1 = b1f + l*NF;
    f32x4 acc[8];
    #pragma unroll
    for(int nt=0; nt<8; nt++){
      float bv = b1[nt*16 + m16];
      acc[nt] = (f32x4){bv,bv,bv,bv};
    }
    const u16* __restrict__ w1 = w1b + l*NF*64;
    #pragma unroll
    for(int k0=0; k0<64; k0+=32){
      bf16x8 a = *(const bf16x8*)&A1[(m0 + m16)*72 + k0 + quad*8];
      #pragma unroll
      for(int nt=0; nt<8; nt++){
        bf16x8 b = *(const bf16x8*)&w1[(nt*16 + m16)*64 + k0 + quad*8];
        acc[nt] = __builtin_amdgcn_mfma_f32_16x16x32_bf16(a, b, acc[nt], 0, 0, 0);
      }
    }
    #pragma unroll
    for(int nt=0; nt<8; nt++){
      #pragma unroll
      for(int r=0; r<4; r++){
        int m = m0 + quad*4 + r;
        A2[m*136 + nt*16 + m16] = f2us(sspf(acc[nt][r]));
      }
    }
  }

  // phase 2: GEMM2, scale by cutoff, store edge-major bf16
  {
    const float* __restrict__ b2 = b2v + l*NF;
    f32x4 acc[8];
    #pragma unroll
    for(int nt=0; nt<8; nt++){
      float bv = b2[nt*16 + m16];
      acc[nt] = (f32x4){bv,bv,bv,bv};
    }
    const u16* __restrict__ w2 = w2b + l*NF*NF;
    #pragma unroll
    for(int k0=0; k0<128; k0+=32){
      bf16x8 a = *(const bf16x8*)&A2[(m0 + m16)*136 + k0 + quad*8];
      #pragma unroll
      for(int nt=0; nt<8; nt++){
        bf16x8 b = *(const bf16x8*)&w2[(nt*16 + m16)*128 + k0 + quad*8];
        acc[nt] = __builtin_amdgcn_mfma_f32_16x16x32_bf16(a, b, acc[nt], 0, 0, 0);
      }
    }
    float cc[4];
    #pragma unroll
    for(int r=0; r<4; r++) cc[r] = cEs[p0 + m0 + quad*4 + r];
    #pragma unroll
    for(int nt=0; nt<8; nt++){
      #pragma unroll
      for(int r=0; r<4; r++){
        int p = p0 + m0 + quad*4 + r;
        Wf[p*NF + nt*16 + m16] = f2us(acc[nt][r]*cc[r]);
      }
    }
  }
}

// ---------- agg[n][f] = sum_p xf[row_s[p]][f] * Wf[p][f] (coalesced, unroll 4) ----------
__global__ void k_gather(const int* __restrict__ col_start, const int* __restrict__ row_s,
                         const float* __restrict__ xf, const u16* __restrict__ Wf,
                         float* __restrict__ agg){
  int n = blockIdx.x;                             // grid: NN
  int f = threadIdx.x;                            // 128
  int p0 = col_start[n], p1 = col_start[n+1];
  float a0=0.f, a1=0.f, a2=0.f, a3=0.f;
  int p = p0;
  for(; p+4 <= p1; p += 4){
    int r0=row_s[p], r1=row_s[p+1], r2=row_s[p+2], r3=row_s[p+3];
    a0 += xf[r0*NF+f]*us2f(Wf[(p  )*NF+f]);
    a1 += xf[r1*NF+f]*us2f(Wf[(p+1)*NF+f]);
    a2 += xf[r2*NF+f]*us2f(Wf[(p+2)*NF+f]);
    a3 += xf[r3*NF+f]*us2f(Wf[(p+3)*NF+f]);
  }
  for(; p<p1; p++) a0 += xf[row_s[p]*NF+f]*us2f(Wf[p*NF+f]);
  agg[n*NF + f] = (a0+a1)+(a2+a3);
}

// ---------- h += ssp(agg@lin2^T + b) @ lin^T + b ----------
__global__ void k_update(const float* __restrict__ agg, const float* __restrict__ l2t,
                         const float* __restrict__ l2bf, const float* __restrict__ lwt,
                         const float* __restrict__ lbf, int l, float* __restrict__ h){
  __shared__ float sg[HH*12];
  int f = threadIdx.x;
  int n0 = blockIdx.x*8;                          // grid exact: NN/8
  const float* __restrict__ wA = l2t + l*NF*HH;
  float bA = l2bf[l*HH + f];
  float acc[8];
  #pragma unroll
  for(int i=0;i<8;i++) acc[i] = bA;
  for(int k=0;k<NF;k++){
    float wv = wA[k*HH + f];
    #pragma unroll
    for(int i=0;i<8;i++) acc[i] += agg[(n0+i)*NF + k] * wv;
  }
  #pragma unroll
  for(int i=0;i<8;i++) sg[f*12 + i] = sspf(acc[i]);
  __syncthreads();
  const float* __restrict__ wB = lwt + l*HH*HH;
  float bB = lbf[l*HH + f];
  float acc2[8];
  #pragma unroll
  for(int i=0;i<8;i++) acc2[i] = bB;
  for(int k=0;k<HH;k++){
    float wv = wB[k*HH + f];
    #pragma unroll
    for(int i=0;i<8;i++) acc2[i] += sg[k*12 + i] * wv;
  }
  #pragma unroll
  for(int i=0;i<8;i++) h[(n0+i)*HH + f] += acc2[i];
}

__global__ void k_out(const float* __restrict__ pos, const float* __restrict__ h,
                      const int* __restrict__ flags, void* __restrict__ out){
  int i = blockIdx.x*256 + threadIdx.x;           // grid exact: NN*HH
  if(flags[0]){
    u16* o = (u16*)out;
    if(i < NN*3) o[i] = f2us(pos[i]);
    o[NN*3 + i] = f2us(h[i]);
  } else {
    float* o = (float*)out;
    if(i < NN*3) o[i] = pos[i];
    o[NN*3 + i] = h[i];
  }
}

extern "C" void kernel_launch(void* const* d_in, const int* in_sizes, int n_in,
                              void* d_out, int out_size, void* d_ws, size_t ws_size,
                              hipStream_t stream){
  const void* z      = d_in[0];
  const void* pos_in = d_in[1];
  const int*  ei_raw = (const int*)d_in[2];
  const void* mlp1_w = d_in[3];
  const void* mlp1_b = d_in[4];
  const void* mlp2_w = d_in[5];
  const void* mlp2_b = d_in[6];
  const void* lin1_w = d_in[7];
  const void* lin2_w = d_in[8];
  const void* lin2_b = d_in[9];
  const void* lin_w  = d_in[10];
  const void* lin_b  = d_in[11];
  const void* coord_w= d_in[12];
  const void* coord_b= d_in[13];

  float* W = (float*)d_ws;
  float* h    = W; W += NN*HH;
  float* xf   = W; W += NN*NF;
  float* agg  = W; W += NN*NF;
  float* pos  = W; W += NN*3;
  float* sums = W; W += NN*3;
  float* wE   = W; W += EE;
  float* cE   = W; W += EE;
  float* wEs  = W; W += EE;
  float* cEs  = W; W += EE;
  float* b1f  = W; W += NL*NF;
  float* b2v  = W; W += NL*NF;
  float* l1t  = W; W += NL*NF*HH;
  float* l2t  = W; W += NL*HH*NF;
  float* l2bf = W; W += NL*HH;
  float* lwt  = W; W += NL*HH*HH;
  float* lbf  = W; W += NL*HH;
  float* cwf  = W; W += NL*(GG+2*HH);
  float* cbf  = W; W += NL;
  W = (float*)(((uintptr_t)W + 63) & ~(uintptr_t)63);   // 16B+ align for bf16x8 loads
  u16* w1b = (u16*)W; W += (NL*NF*64)/2;
  u16* w2b = (u16*)W; W += (NL*NF*NF)/2;
  u16* Wf  = (u16*)W; W += (EE*NF)/2;             // edge-major [p][f] bf16
  int* deg_row   = (int*)W; W += NN;
  int* col_deg   = (int*)W; W += NN;
  int* col_start = (int*)W; W += NN+1;
  int* col_next  = (int*)W; W += NN;
  int* eids      = (int*)W; W += EE;
  int* row_s     = (int*)W; W += EE;
  int* eiN       = (int*)W; W += 2*EE;
  int* flags     = (int*)W; W += 2;

  hipMemsetAsync(deg_row, 0, NN*sizeof(int), stream);
  hipMemsetAsync(col_deg, 0, NN*sizeof(int), stream);

  k_dtype<<<1, 256, 0, stream>>>((const u32*)z, ei_raw, flags);
  k_norm<<<(2*EE)/256, 256, 0, stream>>>(ei_raw, flags, eiN);
  k_prep_weights<<<(NL*NF*NF)/256, 256, 0, stream>>>(
      mlp1_w, mlp1_b, mlp2_w, mlp2_b, lin1_w, lin2_w, lin2_b, lin_w, lin_b,
      coord_w, coord_b, flags,
      b1f, b2v, l1t, l2t, l2bf, lwt, lbf, cwf, cbf, w1b, w2b);
  k_init<<<(NN*HH)/256, 256, 0, stream>>>(z, pos_in, flags, h, pos);
  k_edge_prep<<<EE/256, 256, 0, stream>>>(eiN, pos, wE, cE, deg_row, col_deg);
  k_scan<<<1, 1024, 0, stream>>>(col_deg, col_start, col_next);
  k_fill<<<EE/256, 256, 0, stream>>>(eiN, col_next, eids);
  k_sort<<<EE/256, 256, 0, stream>>>(eids, eiN, wE, cE, row_s, wEs, cEs);

  for(int l=0; l<NL; l++){
    hipMemsetAsync(sums, 0, NN*3*sizeof(float), stream);
    k_coord<<<EE/4, 256, 0, stream>>>(eiN, h, pos, wE, cwf, cbf, l, sums);
    k_posupd<<<(NN+255)/256, 256, 0, stream>>>(pos, sums, deg_row);
    k_xf<<<NN/8, 128, 0, stream>>>(h, l1t, l, xf);
    k_wf<<<EE/64, 256, 0, stream>>>(wEs, cEs, w1b, b1f, w2b, b2v, l, Wf);
    k_gather<<<NN, 128, 0, stream>>>(col_start, row_s, xf, Wf, agg);
    k_update<<<NN/8, 128, 0, stream>>>(agg, l2t, l2bf, lwt, lbf, l, h);
  }
  k_out<<<(NN*HH)/256, 256, 0, stream>>>(pos, h, flags, (void*)d_out);
}

// Round 4
// 1443.919 us; speedup vs baseline: 4.6395x; 1.2944x over previous
//
#include <hip/hip_runtime.h>

// SchNet on MI355X — round 4: linearized coord update (per-node dots + row-CSR
// gather, no atomics/memset, pos ping-pong), bf16 xf for gather, k_wf LDS
// overlay (17.4 KB). bf16-MFMA edge MLP retained.

#define NN 10000
#define EE 320000
#define HH 128
#define GG 50
#define NF 128
#define NL 6

typedef unsigned short u16;
typedef unsigned int u32;
typedef short bf16x8 __attribute__((ext_vector_type(8)));
typedef float f32x4  __attribute__((ext_vector_type(4)));

__device__ __forceinline__ float us2f(u16 u){
  union { float f; u32 i; } v; v.i = ((u32)u) << 16; return v.f;
}
__device__ __forceinline__ u16 f2us(float x){
  union { float f; u32 i; } v; v.f = x;
  u32 r = v.i + 0x7fffu + ((v.i >> 16) & 1u);   // RNE
  return (u16)(r >> 16);
}
__device__ __forceinline__ float ldin(const void* p, int i, int bf){
  return bf ? us2f(((const u16*)p)[i]) : ((const float*)p)[i];
}
__device__ __forceinline__ float sspf(float x){
  return fmaxf(x, 0.f) + __logf(1.f + __expf(-fabsf(x))) - 0.6931472f;
}

// ---------- dtype detection ----------
__global__ void k_dtype(const u32* __restrict__ zraw, const int* __restrict__ ei_raw,
                        int* __restrict__ flags){
  __shared__ int votes[2];
  if(threadIdx.x < 2) votes[threadIdx.x] = 0;
  __syncthreads();
  int v0 = 0, v1 = 0;
  for(int i = threadIdx.x; i < 4096; i += 256){
    u32 w = zraw[i];
    u32 hb = (w >> 8) & 0x7F;
    if(hb >= 0x38 && hb <= 0x41) v0++;
    if(ei_raw[2*i + 1] == 0) v1++;
  }
  atomicAdd(&votes[0], v0); atomicAdd(&votes[1], v1);
  __syncthreads();
  if(threadIdx.x == 0){
    flags[0] = (votes[0] > 2048) ? 1 : 0;
    flags[1] = (votes[1] > 4000) ? 1 : 0;
  }
}

__global__ void k_norm(const int* __restrict__ ei_raw, const int* __restrict__ flags,
                       int* __restrict__ eiN){
  int j = blockIdx.x*256 + threadIdx.x;           // grid exact: 2*EE
  eiN[j] = flags[1] ? ei_raw[2*j] : ei_raw[j];
}

// ---------- weight staging ----------
__global__ void k_prep_weights(
    const void* __restrict__ mlp1_w, const void* __restrict__ mlp1_b,
    const void* __restrict__ mlp2_w, const void* __restrict__ mlp2_b,
    const void* __restrict__ lin1_w, const void* __restrict__ lin2_w,
    const void* __restrict__ lin2_b, const void* __restrict__ lin_w,
    const void* __restrict__ lin_b,  const void* __restrict__ coord_w,
    const void* __restrict__ coord_b, const int* __restrict__ flags,
    float* __restrict__ b1f, float* __restrict__ b2v,
    float* __restrict__ l1t, float* __restrict__ l2t,
    float* __restrict__ l2bf, float* __restrict__ lwt,
    float* __restrict__ lbf, float* __restrict__ cwf, float* __restrict__ cbf,
    u16* __restrict__ w1b, u16* __restrict__ w2b)
{
  int i = blockIdx.x*256 + threadIdx.x;           // grid exact: NL*NF*NF
  int bf = flags[0];
  if(i < NL*NF){
    b1f[i]  = ldin(mlp1_b, i, bf);
    b2v[i]  = ldin(mlp2_b, i, bf);
    l2bf[i] = ldin(lin2_b, i, bf);
    lbf[i]  = ldin(lin_b,  i, bf);
  }
  if(i < NL*NF*64){                               // W1 bf16, K padded 50->64
    int l = i/(NF*64), rem = i%(NF*64);
    int f = rem/64, k = rem%64;
    w1b[i] = (k < GG) ? f2us(ldin(mlp1_w, (l*NF + f)*GG + k, bf)) : (u16)0;
  }
  if(i < NL*NF*NF){
    w2b[i] = f2us(ldin(mlp2_w, i, bf));           // [l][n][k] row-major
    int l = i/(NF*NF), rem = i%(NF*NF);
    int k = rem/NF, f = rem%NF;
    l1t[i] = ldin(lin1_w, l*NF*HH + f*HH + k, bf);
    l2t[i] = ldin(lin2_w, l*HH*NF + f*NF + k, bf);
    lwt[i] = ldin(lin_w,  l*HH*HH + f*HH + k, bf);
  }
  if(i < NL*(GG+2*HH)) cwf[i] = ldin(coord_w, i, bf);
  if(i < NL) cbf[i] = ldin(coord_b, i, bf);
}

__global__ void k_init(const void* __restrict__ z, const void* __restrict__ pos_in,
                       const int* __restrict__ flags,
                       float* __restrict__ h, float* __restrict__ pos){
  int i = blockIdx.x*256 + threadIdx.x;           // grid exact: NN*HH
  int bf = flags[0];
  h[i] = ldin(z, i, bf);
  if(i < NN*3) pos[i] = ldin(pos_in, i, bf);
}

// ---------- edge prep: distances (INITIAL pos), cutoff, degrees ----------
__global__ void k_edge_prep(const int* __restrict__ eiN, const float* __restrict__ pos,
                            float* __restrict__ wE, float* __restrict__ cE,
                            int* __restrict__ deg_row, int* __restrict__ col_deg){
  int e = blockIdx.x*256 + threadIdx.x;           // grid exact: EE
  int r = eiN[e], c = eiN[EE+e];
  float dx = pos[r*3+0]-pos[c*3+0];
  float dy = pos[r*3+1]-pos[c*3+1];
  float dz = pos[r*3+2]-pos[c*3+2];
  float w = sqrtf(dx*dx + dy*dy + dz*dz);
  wE[e] = w;
  cE[e] = 0.5f*(cosf(w*0.3141592653589793f) + 1.f);
  atomicAdd(&deg_row[r], 1);
  atomicAdd(&col_deg[c], 1);
}

// generic single-block exclusive scan (N=10000)
__global__ void k_scan(const int* __restrict__ deg, int* __restrict__ start,
                       int* __restrict__ nxt){
  __shared__ int part[1024];
  int tid = threadIdx.x;
  const int CH = (NN + 1023)/1024;
  int base = tid*CH;
  int s = 0;
  for(int i=0;i<CH;i++){ int idx=base+i; if(idx<NN) s += deg[idx]; }
  part[tid] = s;
  __syncthreads();
  for(int off=1; off<1024; off<<=1){
    int v = (tid>=off) ? part[tid-off] : 0;
    __syncthreads();
    part[tid] += v;
    __syncthreads();
  }
  int run = (tid==0) ? 0 : part[tid-1];
  for(int i=0;i<CH;i++){
    int idx = base+i;
    if(idx<NN){ start[idx]=run; nxt[idx]=run; run += deg[idx]; }
  }
  if(tid==1023) start[NN] = run;
}

// col-CSR fill (for k_gather): scatter row id + edge scalars into col-sorted order
__global__ void k_fillC(const int* __restrict__ eiN, const float* __restrict__ wE,
                        const float* __restrict__ cE, int* __restrict__ col_next,
                        int* __restrict__ row_s, float* __restrict__ wEs,
                        float* __restrict__ cEs){
  int e = blockIdx.x*256 + threadIdx.x;           // grid exact: EE
  int c = eiN[EE+e];
  int p = atomicAdd(&col_next[c], 1);
  row_s[p] = eiN[e];
  wEs[p] = wE[e];
  cEs[p] = cE[e];
}

// row-CSR fill (for k_coordagg)
__global__ void k_fillR(const int* __restrict__ eiN, const float* __restrict__ wE,
                        int* __restrict__ row_next,
                        int* __restrict__ rcol_s, float* __restrict__ rw_s){
  int e = blockIdx.x*256 + threadIdx.x;           // grid exact: EE
  int r = eiN[e];
  int p = atomicAdd(&row_next[r], 1);
  rcol_s[p] = eiN[EE+e];
  rw_s[p] = wE[e];
}

// ---------- per-node dots: d_r[n]=h[n]·cw_row, d_c[n]=h[n]·cw_col ----------
__global__ void k_nodedot(const float* __restrict__ h, const float* __restrict__ cwf,
                          int l, float* __restrict__ d_r, float* __restrict__ d_c){
  int lane = threadIdx.x & 63;
  int n = (blockIdx.x*256 + threadIdx.x) >> 6;    // grid exact: NN/4 blocks
  const float* __restrict__ cw = cwf + l*(GG + 2*HH);
  float h0 = h[n*HH + lane], h1 = h[n*HH + 64 + lane];
  float ar = h0*cw[GG + lane]      + h1*cw[GG + 64 + lane];
  float ac = h0*cw[GG + HH + lane] + h1*cw[GG + HH + 64 + lane];
  #pragma unroll
  for(int s=32; s>0; s>>=1){
    ar += __shfl_down(ar, s, 64);
    ac += __shfl_down(ac, s, 64);
  }
  if(lane == 0){ d_r[n] = ar; d_c[n] = ac; }
}

// ---------- coord update: row-CSR gather + mean + pos add (ping-pong) ----------
__global__ void k_coordagg(const int* __restrict__ row_start, const int* __restrict__ rcol_s,
                           const float* __restrict__ rw_s, const float* __restrict__ d_r,
                           const float* __restrict__ d_c, const float* __restrict__ cwf,
                           const float* __restrict__ cbf, int l,
                           const float* __restrict__ pA, float* __restrict__ pB){
  int lane = threadIdx.x & 63;
  int n = (blockIdx.x*256 + threadIdx.x) >> 6;    // grid exact: NN/4 blocks
  const float* __restrict__ cwg = cwf + l*(GG + 2*HH);
  float cb = cbf[l] + d_r[n];
  int p0 = row_start[n], p1 = row_start[n+1];
  float px = pA[n*3+0], py = pA[n*3+1], pz = pA[n*3+2];
  float sx=0.f, sy=0.f, sz=0.f;
  for(int p = p0 + lane; p < p1; p += 64){
    int c = rcol_s[p];
    float w = rw_s[p];
    float acc = cb + d_c[c];
    #pragma unroll 10
    for(int g=0; g<GG; g++){
      float d = w - (float)g*(10.f/49.f);
      acc += __expf(-12.005f*d*d) * cwg[g];       // cwg[g]: s_load (uniform)
    }
    sx += (px - pA[c*3+0])*acc;
    sy += (py - pA[c*3+1])*acc;
    sz += (pz - pA[c*3+2])*acc;
  }
  #pragma unroll
  for(int s=32; s>0; s>>=1){
    sx += __shfl_down(sx, s, 64);
    sy += __shfl_down(sy, s, 64);
    sz += __shfl_down(sz, s, 64);
  }
  if(lane == 0){
    int cnt = p1 - p0;
    float inv = (cnt > 0) ? 1.f/(float)cnt : 0.f;
    pB[n*3+0] = px + sx*inv;
    pB[n*3+1] = py + sy*inv;
    pB[n*3+2] = pz + sz*inv;
  }
}

// ---------- xf = h @ lin1^T (bf16 out for L2-resident gather) ----------
__global__ void k_xf(const float* __restrict__ h, const float* __restrict__ l1t,
                     int l, u16* __restrict__ xfb){
  int f = threadIdx.x;
  int n0 = blockIdx.x*8;                          // grid exact: NN/8
  const float* __restrict__ wt = l1t + l*HH*NF;
  float acc[8];
  #pragma unroll
  for(int i=0;i<8;i++) acc[i] = 0.f;
  for(int k=0;k<HH;k++){
    float wv = wt[k*NF + f];
    #pragma unroll
    for(int i=0;i<8;i++) acc[i] += h[(n0+i)*HH + k] * wv;
  }
  #pragma unroll
  for(int i=0;i<8;i++) xfb[(n0+i)*NF + f] = f2us(acc[i]);
}

// ---------- edge MLP via bf16 MFMA: 64 edges/block, 4 waves, LDS overlay ----------
__global__ void k_wf(const float* __restrict__ wEs, const float* __restrict__ cEs,
                     const u16* __restrict__ w1b, const float* __restrict__ b1f,
                     const u16* __restrict__ w2b, const float* __restrict__ b2v,
                     int l, u16* __restrict__ Wf){
  __shared__ __align__(16) u16 T[64*136];         // attrs (cols 0..63) then T (0..127)
  int p0 = blockIdx.x*64;                         // grid exact: EE/64
  int t = threadIdx.x;

  // phase 0: attrs -> T cols 0..63 (each wave writes exactly its own 16 rows)
  {
    int e_loc = t >> 2;
    int c0 = (t & 3) * 16;
    float w = wEs[p0 + e_loc];
    u32 q[8];
    #pragma unroll
    for(int j=0;j<8;j++){
      float v0 = 0.f, v1 = 0.f;
      int g0 = c0 + 2*j;
      if(g0 < GG){ float d = w - (float)g0*(10.f/49.f); v0 = __expf(-12.005f*d*d); }
      if(g0+1 < GG){ float d = w - (float)(g0+1)*(10.f/49.f); v1 = __expf(-12.005f*d*d); }
      q[j] = (u32)f2us(v0) | ((u32)f2us(v1) << 16);
    }
    *(uint4*)&T[e_loc*136 + c0]     = make_uint4(q[0],q[1],q[2],q[3]);
    *(uint4*)&T[e_loc*136 + c0 + 8] = make_uint4(q[4],q[5],q[6],q[7]);
  }

  int lane = t & 63;
  int m16  = lane & 15;
  int quad = lane >> 4;
  int m0   = (t >> 6) * 16;                       // wave's row base

  // phase 1: GEMM1 + ssp, overwrite same rows in T (safe: same-wave, after reads)
  {
    const float* __restrict__ b1 = b1f + l*NF;
    f32x4 acc[8];
    #pragma unroll
    for(int nt=0; nt<8; nt++){
      float bv = b1[nt*16 + m16];
      acc[nt] = (f32x4){bv,bv,bv,bv};
    }
    const u16* __restrict__ w1 = w1b + l*NF*64;
    #pragma unroll
    for(int k0=0; k0<64; k0+=32){
      bf16x8 a = *(const bf16x8*)&T[(m0 + m16)*136 + k0 + quad*8];
      #pragma unroll
      for(int nt=0; nt<8; nt++){
        bf16x8 b = *(const bf16x8*)&w1[(nt*16 + m16)*64 + k0 + quad*8];
        acc[nt] = __builtin_amdgcn_mfma_f32_16x16x32_bf16(a, b, acc[nt], 0, 0, 0);
      }
    }
    #pragma unroll
    for(int nt=0; nt<8; nt++){
      #pragma unroll
      for(int r=0; r<4; r++){
        int m = m0 + quad*4 + r;
        T[m*136 + nt*16 + m16] = f2us(sspf(acc[nt][r]));
      }
    }
  }

  // phase 2: GEMM2, scale by cutoff, store edge-major bf16
  {
    const float* __restrict__ b2 = b2v + l*NF;
    f32x4 acc[8];
    #pragma unroll
    for(int nt=0; nt<8; nt++){
      float bv = b2[nt*16 + m16];
      acc[nt] = (f32x4){bv,bv,bv,bv};
    }
    const u16* __restrict__ w2 = w2b + l*NF*NF;
    #pragma unroll
    for(int k0=0; k0<128; k0+=32){
      bf16x8 a = *(const bf16x8*)&T[(m0 + m16)*136 + k0 + quad*8];
      #pragma unroll
      for(int nt=0; nt<8; nt++){
        bf16x8 b = *(const bf16x8*)&w2[(nt*16 + m16)*128 + k0 + quad*8];
        acc[nt] = __builtin_amdgcn_mfma_f32_16x16x32_bf16(a, b, acc[nt], 0, 0, 0);
      }
    }
    float cc[4];
    #pragma unroll
    for(int r=0; r<4; r++) cc[r] = cEs[p0 + m0 + quad*4 + r];
    #pragma unroll
    for(int nt=0; nt<8; nt++){
      #pragma unroll
      for(int r=0; r<4; r++){
        int p = p0 + m0 + quad*4 + r;
        Wf[p*NF + nt*16 + m16] = f2us(acc[nt][r]*cc[r]);
      }
    }
  }
}

// ---------- agg[n][f] = sum_p xf[row_s[p]][f] * Wf[p][f] (2 nodes/block) ----------
__global__ void k_gather(const int* __restrict__ col_start, const int* __restrict__ row_s,
                         const u16* __restrict__ xfb, const u16* __restrict__ Wf,
                         float* __restrict__ agg){
  int n = blockIdx.x*2 + (threadIdx.x >> 7);      // grid exact: NN/2
  int f = threadIdx.x & 127;
  int p0 = col_start[n], p1 = col_start[n+1];
  float a0=0.f, a1=0.f, a2=0.f, a3=0.f;
  int p = p0;
  for(; p+4 <= p1; p += 4){
    int r0=row_s[p], r1=row_s[p+1], r2=row_s[p+2], r3=row_s[p+3];
    a0 += us2f(xfb[r0*NF+f])*us2f(Wf[(p  )*NF+f]);
    a1 += us2f(xfb[r1*NF+f])*us2f(Wf[(p+1)*NF+f]);
    a2 += us2f(xfb[r2*NF+f])*us2f(Wf[(p+2)*NF+f]);
    a3 += us2f(xfb[r3*NF+f])*us2f(Wf[(p+3)*NF+f]);
  }
  for(; p<p1; p++) a0 += us2f(xfb[row_s[p]*NF+f])*us2f(Wf[p*NF+f]);
  agg[n*NF + f] = (a0+a1)+(a2+a3);
}

// ---------- h += ssp(agg@lin2^T + b) @ lin^T + b ----------
__global__ void k_update(const float* __restrict__ agg, const float* __restrict__ l2t,
                         const float* __restrict__ l2bf, const float* __restrict__ lwt,
                         const float* __restrict__ lbf, int l, float* __restrict__ h){
  __shared__ float sg[HH*12];
  int f = threadIdx.x;
  int n0 = blockIdx.x*8;                          // grid exact: NN/8
  const float* __restrict__ wA = l2t + l*NF*HH;
  float bA = l2bf[l*HH + f];
  float acc[8];
  #pragma unroll
  for(int i=0;i<8;i++) acc[i] = bA;
  for(int k=0;k<NF;k++){
    float wv = wA[k*HH + f];
    #pragma unroll
    for(int i=0;i<8;i++) acc[i] += agg[(n0+i)*NF + k] * wv;
  }
  #pragma unroll
  for(int i=0;i<8;i++) sg[f*12 + i] = sspf(acc[i]);
  __syncthreads();
  const float* __restrict__ wB = lwt + l*HH*HH;
  float bB = lbf[l*HH + f];
  float acc2[8];
  #pragma unroll
  for(int i=0;i<8;i++) acc2[i] = bB;
  for(int k=0;k<HH;k++){
    float wv = wB[k*HH + f];
    #pragma unroll
    for(int i=0;i<8;i++) acc2[i] += sg[k*12 + i] * wv;
  }
  #pragma unroll
  for(int i=0;i<8;i++) h[(n0+i)*HH + f] += acc2[i];
}

__global__ void k_out(const float* __restrict__ pos, const float* __restrict__ h,
                      const int* __restrict__ flags, void* __restrict__ out){
  int i = blockIdx.x*256 + threadIdx.x;           // grid exact: NN*HH
  if(flags[0]){
    u16* o = (u16*)out;
    if(i < NN*3) o[i] = f2us(pos[i]);
    o[NN*3 + i] = f2us(h[i]);
  } else {
    float* o = (float*)out;
    if(i < NN*3) o[i] = pos[i];
    o[NN*3 + i] = h[i];
  }
}

extern "C" void kernel_launch(void* const* d_in, const int* in_sizes, int n_in,
                              void* d_out, int out_size, void* d_ws, size_t ws_size,
                              hipStream_t stream){
  const void* z      = d_in[0];
  const void* pos_in = d_in[1];
  const int*  ei_raw = (const int*)d_in[2];
  const void* mlp1_w = d_in[3];
  const void* mlp1_b = d_in[4];
  const void* mlp2_w = d_in[5];
  const void* mlp2_b = d_in[6];
  const void* lin1_w = d_in[7];
  const void* lin2_w = d_in[8];
  const void* lin2_b = d_in[9];
  const void* lin_w  = d_in[10];
  const void* lin_b  = d_in[11];
  const void* coord_w= d_in[12];
  const void* coord_b= d_in[13];

  float* W = (float*)d_ws;
  float* h    = W; W += NN*HH;
  float* agg  = W; W += NN*NF;
  float* posA = W; W += NN*3;
  float* posB = W; W += NN*3;
  float* d_r  = W; W += NN;
  float* d_c  = W; W += NN;
  float* wE   = W; W += EE;
  float* cE   = W; W += EE;
  float* wEs  = W; W += EE;
  float* cEs  = W; W += EE;
  float* rw_s = W; W += EE;
  float* b1f  = W; W += NL*NF;
  float* b2v  = W; W += NL*NF;
  float* l1t  = W; W += NL*NF*HH;
  float* l2t  = W; W += NL*HH*NF;
  float* l2bf = W; W += NL*HH;
  float* lwt  = W; W += NL*HH*HH;
  float* lbf  = W; W += NL*HH;
  float* cwf  = W; W += NL*(GG+2*HH);
  float* cbf  = W; W += NL;
  W = (float*)(((uintptr_t)W + 63) & ~(uintptr_t)63);
  u16* w1b = (u16*)W; W += (NL*NF*64)/2;
  u16* w2b = (u16*)W; W += (NL*NF*NF)/2;
  u16* Wf  = (u16*)W; W += (EE*NF)/2;             // edge-major [p][f] bf16
  u16* xfb = (u16*)W; W += (NN*NF)/2;             // bf16 xf
  int* deg_row   = (int*)W; W += NN;
  int* col_deg   = (int*)W; W += NN;
  int* col_start = (int*)W; W += NN+1;
  int* col_next  = (int*)W; W += NN;
  int* row_start = (int*)W; W += NN+1;
  int* row_next  = (int*)W; W += NN;
  int* row_s     = (int*)W; W += EE;
  int* rcol_s    = (int*)W; W += EE;
  int* eiN       = (int*)W; W += 2*EE;
  int* flags     = (int*)W; W += 2;

  hipMemsetAsync(deg_row, 0, NN*sizeof(int), stream);
  hipMemsetAsync(col_deg, 0, NN*sizeof(int), stream);

  k_dtype<<<1, 256, 0, stream>>>((const u32*)z, ei_raw, flags);
  k_norm<<<(2*EE)/256, 256, 0, stream>>>(ei_raw, flags, eiN);
  k_prep_weights<<<(NL*NF*NF)/256, 256, 0, stream>>>(
      mlp1_w, mlp1_b, mlp2_w, mlp2_b, lin1_w, lin2_w, lin2_b, lin_w, lin_b,
      coord_w, coord_b, flags,
      b1f, b2v, l1t, l2t, l2bf, lwt, lbf, cwf, cbf, w1b, w2b);
  k_init<<<(NN*HH)/256, 256, 0, stream>>>(z, pos_in, flags, h, posA);
  k_edge_prep<<<EE/256, 256, 0, stream>>>(eiN, posA, wE, cE, deg_row, col_deg);
  k_scan<<<1, 1024, 0, stream>>>(col_deg, col_start, col_next);
  k_scan<<<1, 1024, 0, stream>>>(deg_row, row_start, row_next);
  k_fillC<<<EE/256, 256, 0, stream>>>(eiN, wE, cE, col_next, row_s, wEs, cEs);
  k_fillR<<<EE/256, 256, 0, stream>>>(eiN, wE, row_next, rcol_s, rw_s);

  float* pA = posA;
  float* pB = posB;
  for(int l=0; l<NL; l++){
    k_nodedot<<<NN/4, 256, 0, stream>>>(h, cwf, l, d_r, d_c);
    k_coordagg<<<NN/4, 256, 0, stream>>>(row_start, rcol_s, rw_s, d_r, d_c,
                                         cwf, cbf, l, pA, pB);
    k_xf<<<NN/8, 128, 0, stream>>>(h, l1t, l, xfb);
    k_wf<<<EE/64, 256, 0, stream>>>(wEs, cEs, w1b, b1f, w2b, b2v, l, Wf);
    k_gather<<<NN/2, 256, 0, stream>>>(col_start, row_s, xfb, Wf, agg);
    k_update<<<NN/8, 128, 0, stream>>>(agg, l2t, l2bf, lwt, lbf, l, h);
    float* tmp = pA; pA = pB; pB = tmp;
  }
  // NL even -> final pos is back in posA (== pA after 6 swaps)
  k_out<<<(NN*HH)/256, 256, 0, stream>>>(pA, h, flags, (void*)d_out);
}